// Round 1
// baseline (899.978 us; speedup 1.0000x reference)
//
#include <hip/hip_runtime.h>

typedef unsigned short u16;
typedef unsigned int u32;
typedef __bf16 bf16x8 __attribute__((ext_vector_type(8)));
typedef float f32x4 __attribute__((ext_vector_type(4)));
typedef u16 u16x8 __attribute__((ext_vector_type(8)));

#define NTOK 8192
#define CDIM 1024
#define NEXP 8
#define FEDIM 1024
#define FSDIM 4096

#define GLD16(gp, lp) __builtin_amdgcn_global_load_lds( \
    (const __attribute__((address_space(1))) void*)(gp), \
    (__attribute__((address_space(3))) void*)(lp), 16, 0, 0)

__device__ __forceinline__ u16 f2bf(float f) {
  u32 u = __float_as_uint(f);
  u += 0x7FFFu + ((u >> 16) & 1u);   // RNE
  return (u16)(u >> 16);
}
__device__ __forceinline__ float bf2f(u16 h) {
  return __uint_as_float(((u32)h) << 16);
}

// ---------------- gate: scores, softmax, top-2, expert lists ----------------
__global__ __launch_bounds__(256) void gate_kernel(
    const float* __restrict__ x, const float* __restrict__ gw,
    float* __restrict__ scores, int* __restrict__ cnt,
    int* __restrict__ tok, float* __restrict__ wgt)
{
  int wave = threadIdx.x >> 6, lane = threadIdx.x & 63;
  int n = blockIdx.x * 4 + wave;
  const float4* xr = (const float4*)(x + (size_t)n * CDIM) + lane * 4;
  float4 xv[4];
#pragma unroll
  for (int j = 0; j < 4; j++) xv[j] = xr[j];
  float s[NEXP];
#pragma unroll
  for (int e = 0; e < NEXP; e++) {
    const float4* g = (const float4*)(gw + (size_t)e * CDIM) + lane * 4;
    float a = 0.f;
#pragma unroll
    for (int j = 0; j < 4; j++) {
      float4 gv = g[j];
      a += xv[j].x * gv.x + xv[j].y * gv.y + xv[j].z * gv.z + xv[j].w * gv.w;
    }
#pragma unroll
    for (int o = 32; o > 0; o >>= 1) a += __shfl_xor(a, o);
    s[e] = a;
  }
  if (lane == 0) {
    float m = s[0];
    for (int e = 1; e < NEXP; e++) m = fmaxf(m, s[e]);
    float p[NEXP], sum = 0.f;
    for (int e = 0; e < NEXP; e++) { p[e] = expf(s[e] - m); sum += p[e]; }
    int i1 = 0;
    for (int e = 1; e < NEXP; e++) if (p[e] > p[i1]) i1 = e;
    int i2 = (i1 == 0) ? 1 : 0;
    for (int e = 0; e < NEXP; e++) if (e != i1 && p[e] > p[i2]) i2 = e;
    float w1 = p[i1] / sum, w2 = p[i2] / sum;
#pragma unroll
    for (int e = 0; e < NEXP; e++) scores[(size_t)n * NEXP + e] = s[e];
    int pos = atomicAdd(&cnt[i1], 1);
    tok[i1 * NTOK + pos] = n; wgt[i1 * NTOK + pos] = w1;
    pos = atomicAdd(&cnt[i2], 1);
    tok[i2 * NTOK + pos] = n; wgt[i2 * NTOK + pos] = w2;
  }
}

__global__ void prefix_kernel(const int* __restrict__ cnt, int* __restrict__ prefix) {
  if (threadIdx.x == 0 && blockIdx.x == 0) {
    int a = 0;
    for (int e = 0; e < NEXP; e++) { prefix[e] = a; a += cnt[e]; }
    prefix[NEXP] = a;
  }
}

// ---------------- f32 -> bf16 conversion of x ----------------
__global__ __launch_bounds__(256) void convx_kernel(const float* __restrict__ x,
                                                    u16* __restrict__ xb)
{
  size_t i = (size_t)blockIdx.x * 256 + threadIdx.x;   // group of 8 elements
  const float4* src = (const float4*)x + i * 2;
  float4 a = src[0], b = src[1];
  u16x8 r;
  r[0] = f2bf(a.x); r[1] = f2bf(a.y); r[2] = f2bf(a.z); r[3] = f2bf(a.w);
  r[4] = f2bf(b.x); r[5] = f2bf(b.y); r[6] = f2bf(b.z); r[7] = f2bf(b.w);
  *((u16x8*)xb + i) = r;
}

// ---------------- tiled transpose f32[R][C] -> bf16[C][R], batched in z ------
__global__ __launch_bounds__(256) void transpose_kernel(const float* __restrict__ src,
    u16* __restrict__ dst, int R, int C)
{
  __shared__ float tile[32][33];
  size_t base = (size_t)blockIdx.z * R * C;
  int c0 = blockIdx.x * 32, r0 = blockIdx.y * 32;
  int tx = threadIdx.x & 31, ty = threadIdx.x >> 5;
#pragma unroll
  for (int i = 0; i < 4; i++) {
    int r = ty + i * 8;
    tile[r][tx] = src[base + (size_t)(r0 + r) * C + c0 + tx];
  }
  __syncthreads();
#pragma unroll
  for (int i = 0; i < 4; i++) {
    int c = ty + i * 8;
    dst[base + (size_t)(c0 + c) * R + r0 + tx] = f2bf(tile[tx][c]);
  }
}

// ---------------- 128x128xBK32 bf16 MFMA GEMM (m97 structure) ----------------
// A: bf16 [*, lda] row-major.  B: bf16 B^T layout [ncols][ldb] (row n = output
// column n over K).  EPI: 0 store-bf16 g1, 1 SwiGLU(g1)*acc -> h, 2 store f32,
// 3 add f32, 4 scale-by-weight + atomicAdd scatter to out rows tok[].
// AMODE: 0 direct rows, 1 rows gathered via tok list (expert in/x),
//        2 rows at prefix[e]+r (expert h).
#define BM 128
#define BN 128
#define BK 32

template<int EPI, int AMODE>
__global__ __launch_bounds__(256) void gemm128(
    const u16* __restrict__ A, int lda,
    const u16* __restrict__ B, size_t bstride, int ldb,
    int M, int K,
    u16* __restrict__ g1, u16* __restrict__ hbuf, int ldg,
    float* __restrict__ outF, int ldo,
    const int* __restrict__ cnt, const int* __restrict__ prefix,
    const int* __restrict__ tok, const float* __restrict__ wgt)
{
  int e = blockIdx.z;
  int Mloc = (AMODE == 0) ? M : cnt[e];
  int mbase = blockIdx.y * BM;
  if (AMODE != 0 && mbase >= Mloc) return;
  int nbase = blockIdx.x * BN;
  int tid = threadIdx.x, wid = tid >> 6, lane = tid & 63;

  __shared__ __align__(16) u16 As[BM * BK];
  __shared__ __align__(16) u16 Bs[BN * BK];

  int sr = lane >> 2;             // 0..15 row within a 16-row staging group
  int kg = (lane & 3) * 8;        // k element offset (8 bf16 = 16B per lane)
  int arow0 = wid * 32 + sr;
  int arow1 = arow0 + 16;

  int pfx = (AMODE == 0) ? 0 : prefix[e];
  size_t r0, r1;
  if (AMODE == 0) {
    r0 = mbase + arow0; r1 = mbase + arow1;
  } else if (AMODE == 1) {
    r0 = tok[e * NTOK + min(mbase + arow0, Mloc - 1)];
    r1 = tok[e * NTOK + min(mbase + arow1, Mloc - 1)];
  } else {
    r0 = pfx + min(mbase + arow0, Mloc - 1);
    r1 = pfx + min(mbase + arow1, Mloc - 1);
  }

  const u16* Ap0 = A + r0 * (size_t)lda + kg;
  const u16* Ap1 = A + r1 * (size_t)lda + kg;
  const u16* Bb = B + ((AMODE != 0) ? (size_t)e * bstride : 0);
  const u16* Bp0 = Bb + (size_t)(nbase + arow0) * ldb + kg;
  const u16* Bp1 = Bb + (size_t)(nbase + arow1) * ldb + kg;

  u16* AsW0 = &As[(wid * 32) * BK];
  u16* AsW1 = &As[(wid * 32 + 16) * BK];
  u16* BsW0 = &Bs[(wid * 32) * BK];
  u16* BsW1 = &Bs[(wid * 32 + 16) * BK];

  int wr = wid >> 1, wc = wid & 1;
  int fr = lane & 15, fgk = (lane >> 4) * 8;

  f32x4 acc[4][4] = {};

  for (int k0 = 0; k0 < K; k0 += BK) {
    GLD16(Ap0, AsW0); GLD16(Ap1, AsW1);
    GLD16(Bp0, BsW0); GLD16(Bp1, BsW1);
    Ap0 += BK; Ap1 += BK; Bp0 += BK; Bp1 += BK;
    __syncthreads();   // drains vmcnt -> LDS tiles visible
    bf16x8 af[4], bfr[4];
#pragma unroll
    for (int m = 0; m < 4; m++)
      af[m] = *(const bf16x8*)&As[(wr * 64 + m * 16 + fr) * BK + fgk];
#pragma unroll
    for (int n = 0; n < 4; n++)
      bfr[n] = *(const bf16x8*)&Bs[(wc * 64 + n * 16 + fr) * BK + fgk];
#pragma unroll
    for (int m = 0; m < 4; m++)
#pragma unroll
      for (int n = 0; n < 4; n++)
        acc[m][n] = __builtin_amdgcn_mfma_f32_16x16x32_bf16(af[m], bfr[n], acc[m][n], 0, 0, 0);
    __syncthreads();
  }

  // epilogue — C/D layout: col = lane&15, row = (lane>>4)*4 + j  [m89-verified]
  int fg4 = (lane >> 4) * 4;
#pragma unroll
  for (int m = 0; m < 4; m++) {
#pragma unroll
    for (int j = 0; j < 4; j++) {
      int rloc = wr * 64 + m * 16 + fg4 + j;
      int rr = mbase + rloc;
      if (AMODE != 0 && rr >= Mloc) continue;
      int t = 0; float wv = 0.f;
      if (EPI == 4) { t = tok[e * NTOK + rr]; wv = wgt[e * NTOK + rr]; }
      size_t orow = (size_t)(pfx + rr);
#pragma unroll
      for (int n = 0; n < 4; n++) {
        int col = nbase + wc * 64 + n * 16 + fr;
        float v = acc[m][n][j];
        if (EPI == 0) {
          g1[orow * ldg + col] = f2bf(v);
        } else if (EPI == 1) {
          float gv = bf2f(g1[orow * ldg + col]);
          float hv = (gv / (1.f + __expf(-gv))) * v;   // silu(g1)*g2
          hbuf[orow * ldg + col] = f2bf(hv);
        } else if (EPI == 2) {
          outF[(size_t)rr * ldo + col] = v;
        } else if (EPI == 3) {
          outF[(size_t)rr * ldo + col] += v;
        } else {
          unsafeAtomicAdd(&outF[(size_t)t * ldo + col], v * wv);
        }
      }
    }
  }
}

// ---------------- host ----------------
extern "C" void kernel_launch(void* const* d_in, const int* in_sizes, int n_in,
                              void* d_out, int out_size, void* d_ws, size_t ws_size,
                              hipStream_t stream)
{
  const float* x   = (const float*)d_in[0];
  const float* gw  = (const float*)d_in[1];
  const float* ew1 = (const float*)d_in[2];
  const float* ew2 = (const float*)d_in[3];
  const float* ewp = (const float*)d_in[4];
  const float* sw1 = (const float*)d_in[5];
  const float* sw2 = (const float*)d_in[6];
  const float* swp = (const float*)d_in[7];
  float* out    = (float*)d_out;
  float* scores = out + (size_t)NTOK * CDIM;

  char* wsp = (char*)d_ws;
  size_t off = 0;
  auto alloc = [&](size_t bytes) -> void* {
    void* p = wsp + off; off += (bytes + 255) & ~(size_t)255; return p;
  };
  u16* xb   = (u16*)alloc((size_t)NTOK * CDIM * 2);
  u16* ew1t = (u16*)alloc((size_t)NEXP * FEDIM * CDIM * 2);
  u16* ew2t = (u16*)alloc((size_t)NEXP * FEDIM * CDIM * 2);
  u16* ewpt = (u16*)alloc((size_t)NEXP * CDIM * FEDIM * 2);
  u16* sw1t = (u16*)alloc((size_t)FSDIM * CDIM * 2);
  u16* sw2t = (u16*)alloc((size_t)FSDIM * CDIM * 2);
  u16* swpt = (u16*)alloc((size_t)CDIM * FSDIM * 2);
  u16* g1   = (u16*)alloc((size_t)2 * NTOK * 1024 * 2);   // 16384 x 1024 bf16
  u16* hbuf = (u16*)alloc((size_t)2 * NTOK * 1024 * 2);
  int* cnt  = (int*)alloc(256);
  int* pfx  = (int*)alloc(256);
  int* tok  = (int*)alloc((size_t)NEXP * NTOK * 4);
  float* wgt = (float*)alloc((size_t)NEXP * NTOK * 4);
  if (off > ws_size) return;  // workspace too small -> will show as full-absmax fail

  hipMemsetAsync(cnt, 0, 32, stream);
  gate_kernel<<<NTOK / 4, 256, 0, stream>>>(x, gw, scores, cnt, tok, wgt);
  prefix_kernel<<<1, 64, 0, stream>>>(cnt, pfx);
  convx_kernel<<<(NTOK * CDIM) / (256 * 8), 256, 0, stream>>>(x, xb);
  transpose_kernel<<<dim3(FEDIM/32, CDIM/32, NEXP), 256, 0, stream>>>(ew1, ew1t, CDIM, FEDIM);
  transpose_kernel<<<dim3(FEDIM/32, CDIM/32, NEXP), 256, 0, stream>>>(ew2, ew2t, CDIM, FEDIM);
  transpose_kernel<<<dim3(CDIM/32, FEDIM/32, NEXP), 256, 0, stream>>>(ewp, ewpt, FEDIM, CDIM);
  transpose_kernel<<<dim3(FSDIM/32, CDIM/32, 1), 256, 0, stream>>>(sw1, sw1t, CDIM, FSDIM);
  transpose_kernel<<<dim3(FSDIM/32, CDIM/32, 1), 256, 0, stream>>>(sw2, sw2t, CDIM, FSDIM);
  transpose_kernel<<<dim3(CDIM/32, FSDIM/32, 1), 256, 0, stream>>>(swp, swpt, FSDIM, CDIM);

  // shared FFN in two FS-slices of 2048 (reuses g1/hbuf)
  for (int s = 0; s < 2; s++) {
    const u16* b1 = sw1t + (size_t)s * 2048 * CDIM;
    const u16* b2 = sw2t + (size_t)s * 2048 * CDIM;
    const u16* bp = swpt + (size_t)s * 2048;
    gemm128<0,0><<<dim3(16, 64, 1), 256, 0, stream>>>(xb, CDIM, b1, 0, CDIM, NTOK, CDIM,
        g1, nullptr, 2048, nullptr, 0, nullptr, nullptr, nullptr, nullptr);
    gemm128<1,0><<<dim3(16, 64, 1), 256, 0, stream>>>(xb, CDIM, b2, 0, CDIM, NTOK, CDIM,
        g1, hbuf, 2048, nullptr, 0, nullptr, nullptr, nullptr, nullptr);
    if (s == 0)
      gemm128<2,0><<<dim3(8, 64, 1), 256, 0, stream>>>(hbuf, 2048, bp, 0, FSDIM, NTOK, 2048,
          nullptr, nullptr, 0, out, CDIM, nullptr, nullptr, nullptr, nullptr);
    else
      gemm128<3,0><<<dim3(8, 64, 1), 256, 0, stream>>>(hbuf, 2048, bp, 0, FSDIM, NTOK, 2048,
          nullptr, nullptr, 0, out, CDIM, nullptr, nullptr, nullptr, nullptr);
  }

  // experts on gathered (compacted) rows
  size_t estride = (size_t)FEDIM * CDIM;
  gemm128<0,1><<<dim3(8, 64, NEXP), 256, 0, stream>>>(xb, CDIM, ew1t, estride, CDIM, 0, CDIM,
      g1, nullptr, FEDIM, nullptr, 0, cnt, pfx, tok, wgt);
  gemm128<1,1><<<dim3(8, 64, NEXP), 256, 0, stream>>>(xb, CDIM, ew2t, estride, CDIM, 0, CDIM,
      g1, hbuf, FEDIM, nullptr, 0, cnt, pfx, tok, wgt);
  gemm128<4,2><<<dim3(8, 64, NEXP), 256, 0, stream>>>(hbuf, FEDIM, ewpt, estride, FEDIM, 0, FEDIM,
      nullptr, nullptr, 0, out, CDIM, cnt, pfx, tok, wgt);
}